// Round 10
// baseline (165.352 us; speedup 1.0000x reference)
//
#include <hip/hip_runtime.h>

// DiceLoss: B=2, C=14, D=48, H=256, W=256, organs 1..13, weights all 1.0.
// Per batch b: S = sum of pred at target channel (t in 1..13),
//              Q = sum over c=1..13 of pred[c]^2, cnt = #{t>=1}.
// dice_stage = 2S/(Q + cnt + 13*EPS); out = mean_b(2 - dice1 - dice2).
//
// R10 = R6 skeleton (2 streams/block, 2048 blocks = 8/CU, counted vmcnt,
// no barriers) with ONE mechanism change: DUAL RETURN PATHS.
//   stage-1 tiles -> global_load_lds ring (4 slots, as R6)
//   stage-2 tiles -> 3-deep register pipeline (r0..r2)
// issued strictly pair-interleaved so each pair (c,p) has exactly 4 newer
// loads outstanding at its consume point -> wait vmcnt(4) (tail 4/2/0).
// Tests whether R6's ~5.2 TB/s cap is the LDS-write return path; if flat,
// the cap is upstream (L3/fabric read BW) = roofline.
// Also: prologue issued BEFORE target read (overlap its latency).

namespace {
constexpr int BATCH = 2;
constexpr int CH = 14;
constexpr int ORGANS = 13;
constexpr unsigned NV4 = 786432u;        // vec4 groups per (b, channel) slice
constexpr int TPB = 256;
constexpr int NBLK = 2048;               // 1024 windows per batch, 8/CU
constexpr unsigned WIN = 768u;           // groups per window (1024*768 = NV4)
constexpr double EPS = 1e-05;
}

// global -> LDS async, 16B/lane, default cache policy (NT hurt: R7).
#define LOADLDS(srcptr, slot)                                              \
    __builtin_amdgcn_global_load_lds(                                      \
        (const __attribute__((address_space(1))) unsigned*)(srcptr),       \
        (__attribute__((address_space(3))) unsigned*)&ring[(slot)][ldsq],  \
        16, 0, 0)

__global__ __launch_bounds__(TPB, 8) void dice_lds(
    const float* __restrict__ p1g, const float* __restrict__ p2g,
    const int* __restrict__ tg, double* __restrict__ part)
{
    __shared__ float4 ring[4][TPB];      // 16 KB ring (stage-1 path)
    __shared__ float red[4][5];

    const unsigned blk = blockIdx.x;
    const unsigned b = blk >> 10;                // batch
    const unsigned w0 = (blk & 1023u) * WIN;     // window start (groups)
    const unsigned tid = threadIdx.x;
    const unsigned wid = tid >> 6;
    const unsigned ldsq = wid * 64u;             // this wave's ring quarter

    // Walkers at channel 1 of each stage (float4 idx space, + tid).
    const float4* rw = reinterpret_cast<const float4*>(p1g)
        + (unsigned long long)(b * CH + 1) * NV4 + w0 + tid;   // stage1 -> LDS
    const float4* gw = reinterpret_cast<const float4*>(p2g)
        + (unsigned long long)(b * CH + 1) * NV4 + w0 + tid;   // stage2 -> regs

    // Prologue: channel-1 pairs (R,G)x3 in flight BEFORE the target read.
    LOADLDS(rw + 0 * TPB, 0);
    float4 r0 = gw[0 * TPB];
    LOADLDS(rw + 1 * TPB, 1);
    float4 r1 = gw[1 * TPB];
    LOADLDS(rw + 2 * TPB, 2);
    float4 r2 = gw[2 * TPB];

    // Target window once: 3 int4 per thread; pack labels into bytes.
    // (Compiler's wait for t decode drains prologue too - one latency window.)
    unsigned tw[3];
    float cn = 0.f;
    {
        const int4* __restrict__ pT =
            reinterpret_cast<const int4*>(tg) + b * NV4 + w0;
        #pragma unroll
        for (int k = 0; k < 3; ++k) {
            const int4 t = pT[k * TPB + tid];
            cn += (float)((t.x > 0) + (t.y > 0) + (t.z > 0) + (t.w > 0));
            tw[k] = (unsigned)t.x | ((unsigned)t.y << 8)
                  | ((unsigned)t.z << 16) | ((unsigned)t.w << 24);
        }
    }

    float s1 = 0.f, q1 = 0.f, s2 = 0.f, q2 = 0.f;
    unsigned cc = 1;                             // current organ id

    auto acc4 = [&](const float4 A, const unsigned t4, float& q, float& s) {
        q = fmaf(A.x, A.x, q); q = fmaf(A.y, A.y, q);
        q = fmaf(A.z, A.z, q); q = fmaf(A.w, A.w, q);
        const bool ex = ((t4 & 255u) == cc);
        const bool ey = (((t4 >> 8) & 255u) == cc);
        const bool ez = (((t4 >> 16) & 255u) == cc);
        const bool ew = ((t4 >> 24) == cc);
        s += (ex ? A.x : 0.f) + (ey ? A.y : 0.f)
           + (ez ? A.z : 0.f) + (ew ? A.w : 0.f);
    };

    // One step: wait until pair (c,p) landed (exactly 4 newer loads
    // outstanding), issue pair (c+1,p), consume ring tile + reg tile.
    // Ring slot of (c,p) is (SB+p)&3 with SB = (3(c-1))&3; the issue
    // overwrites slot (SB+p+3)&3, whose occupant was consumed last step.
#define STEP(p, rp, SB)                                                    \
    asm volatile("s_waitcnt vmcnt(4)" ::: "memory");                       \
    LOADLDS(rw + NV4 + (p) * TPB, ((SB) + 3 + (p)) & 3);                   \
    acc4(ring[((SB) + (p)) & 3][tid], tw[p], q1, s1);                      \
    acc4(rp, tw[p], q2, s2);                                               \
    rp = gw[NV4 + (p) * TPB];

#define CHAN(SB)                                                           \
    STEP(0, r0, SB) STEP(1, r1, SB) STEP(2, r2, SB)                        \
    rw += NV4; gw += NV4; ++cc;

    // Channels 1..12 (SB cycles 0,3,2,1).
    #pragma unroll 1
    for (int g4 = 0; g4 < 3; ++g4) {
        CHAN(0) CHAN(3) CHAN(2) CHAN(1)
    }

    // Tail: channel 13 (SB = 36 & 3 = 0), nothing left to issue.
    asm volatile("s_waitcnt vmcnt(4)" ::: "memory");
    acc4(ring[0][tid], tw[0], q1, s1);
    acc4(r0, tw[0], q2, s2);
    asm volatile("s_waitcnt vmcnt(2)" ::: "memory");
    acc4(ring[1][tid], tw[1], q1, s1);
    acc4(r1, tw[1], q2, s2);
    asm volatile("s_waitcnt vmcnt(0)" ::: "memory");
    acc4(ring[2][tid], tw[2], q1, s1);
    acc4(r2, tw[2], q2, s2);

#undef CHAN
#undef STEP

    // ---- Block reduction: wave shuffle then LDS across 4 waves ----
    float vals[5] = {s1, q1, s2, q2, cn};
    #pragma unroll
    for (int k = 0; k < 5; ++k) {
        float v = vals[k];
        #pragma unroll
        for (int off = 32; off > 0; off >>= 1) v += __shfl_down(v, off, 64);
        vals[k] = v;
    }
    const int lane = tid & 63;
    if (lane == 0) {
        #pragma unroll
        for (int k = 0; k < 5; ++k) red[wid][k] = vals[k];
    }
    __syncthreads();
    if (tid == 0) {
        #pragma unroll
        for (int k = 0; k < 5; ++k)
            part[blk * 5 + k] =
                (double)(red[0][k] + red[1][k] + red[2][k] + red[3][k]);
    }
}

__global__ __launch_bounds__(256) void dice_final(
    const double* __restrict__ part, float* __restrict__ out)
{
    __shared__ double redd[BATCH][4][5];
    const int tid = threadIdx.x, lane = tid & 63, wv = tid >> 6;
    #pragma unroll
    for (int b = 0; b < BATCH; ++b) {
        double loc[5] = {0, 0, 0, 0, 0};
        for (int i = tid; i < NBLK / BATCH; i += 256) {
            const double* p = part + ((unsigned)(b * (NBLK / BATCH) + i)) * 5u;
            #pragma unroll
            for (int k = 0; k < 5; ++k) loc[k] += p[k];
        }
        #pragma unroll
        for (int k = 0; k < 5; ++k) {
            double v = loc[k];
            #pragma unroll
            for (int off = 32; off > 0; off >>= 1) v += __shfl_down(v, off, 64);
            loc[k] = v;
        }
        if (lane == 0) {
            #pragma unroll
            for (int k = 0; k < 5; ++k) redd[b][wv][k] = loc[k];
        }
    }
    __syncthreads();
    if (tid == 0) {
        double total = 0.0;
        #pragma unroll
        for (int b = 0; b < BATCH; ++b) {
            double a[5];
            #pragma unroll
            for (int k = 0; k < 5; ++k)
                a[k] = redd[b][0][k] + redd[b][1][k] + redd[b][2][k] + redd[b][3][k];
            const double den1 = a[1] + a[4] + (double)ORGANS * EPS;
            const double den2 = a[3] + a[4] + (double)ORGANS * EPS;
            total += 2.0 - (2.0 * a[0] / den1 + 2.0 * a[2] / den2);
        }
        *out = (float)(total / BATCH);
    }
}

extern "C" void kernel_launch(void* const* d_in, const int* in_sizes, int n_in,
                              void* d_out, int out_size, void* d_ws, size_t ws_size,
                              hipStream_t stream)
{
    const float* p1 = (const float*)d_in[0];
    const float* p2 = (const float*)d_in[1];
    const int* tg = (const int*)d_in[2];
    float* out = (float*)d_out;
    double* part = (double*)d_ws;    // 2048*5 doubles = 80 KB; all written per call

    dice_lds<<<dim3(NBLK), dim3(TPB), 0, stream>>>(p1, p2, tg, part);
    dice_final<<<1, 256, 0, stream>>>(part, out);
}

// Round 11
// 159.115 us; speedup vs baseline: 1.0392x; 1.0392x over previous
//
#include <hip/hip_runtime.h>

// DiceLoss: B=2, C=14, D=48, H=256, W=256, organs 1..13, weights all 1.0.
// Per batch b: S = sum of pred at target channel (t in 1..13),
//              Q = sum over c=1..13 of pred[c]^2, cnt = #{t>=1}.
// dice_stage = 2S/(Q + cnt + 13*EPS); out = mean_b(2 - dice1 - dice2).
//
// R11 = R6 (best, 139us: LDS ring, global_load_lds w16 aux=0, counted
// vmcnt(2), no barriers, 2 streams/block, 32 waves/CU) with ONE axis:
// TPB 256->512, NBLK 2048->1024 (4 blocks/CU x 8 waves = same 32 waves/CU,
// same streams/block). Contiguous run per stream doubles to 24 KB; chip
// stream count halves. Ring slots 8 KB -> 32 KB LDS/block (128 KB/CU ok).
// Plus prologue issued BEFORE the target read (overlap its latency).

namespace {
constexpr int BATCH = 2;
constexpr int CH = 14;
constexpr int ORGANS = 13;
constexpr unsigned NV4 = 786432u;        // vec4 groups per (b, channel) slice
constexpr int TPB = 512;
constexpr int NBLK = 1024;               // 512 windows per batch, 4/CU
constexpr unsigned WIN = 1536u;          // groups per window (512*1536 = NV4)
constexpr double EPS = 1e-05;
}

// global -> LDS async, 16B/lane, default cache policy (NT hurt: R7).
#define LOADLDS(srcptr, slot)                                              \
    __builtin_amdgcn_global_load_lds(                                      \
        (const __attribute__((address_space(1))) unsigned*)(srcptr),       \
        (__attribute__((address_space(3))) unsigned*)&ring[(slot)][ldsq],  \
        16, 0, 0)

__global__ __launch_bounds__(TPB, 8) void dice_lds(
    const float* __restrict__ p1g, const float* __restrict__ p2g,
    const int* __restrict__ tg, double* __restrict__ part)
{
    __shared__ float4 ring[4][TPB];      // 32 KB ring, slot = tile & 3
    __shared__ float red[8][5];

    const unsigned blk = blockIdx.x;
    const unsigned b = blk >> 9;                 // batch
    const unsigned w0 = (blk & 511u) * WIN;      // window start (groups)
    const unsigned tid = threadIdx.x;
    const unsigned wid = tid >> 6;               // 0..7
    const unsigned ldsq = wid * 64u;             // this wave's ring eighth

    // Channel walkers (float4 index space), start at channel 1 of each stage.
    const float4* a0 = reinterpret_cast<const float4*>(p1g)
        + (unsigned long long)(b * CH + 1) * NV4 + w0 + tid;
    const float4* a1 = reinterpret_cast<const float4*>(p2g)
        + (unsigned long long)(b * CH + 1) * NV4 + w0 + tid;

    // Prologue FIRST: tiles 0..2 (stage1, channel 1) in flight before the
    // target read, so HBM is busy during its round-trip.
    LOADLDS(a0 + 0 * TPB, 0);
    LOADLDS(a0 + 1 * TPB, 1);
    LOADLDS(a0 + 2 * TPB, 2);

    // Target window once: 3 int4 per thread; pack labels into bytes.
    unsigned tw[3];
    float cn = 0.f;
    {
        const int4* __restrict__ pT =
            reinterpret_cast<const int4*>(tg) + b * NV4 + w0;
        #pragma unroll
        for (int k = 0; k < 3; ++k) {
            const int4 t = pT[k * TPB + tid];
            cn += (float)((t.x > 0) + (t.y > 0) + (t.z > 0) + (t.w > 0));
            tw[k] = (unsigned)t.x | ((unsigned)t.y << 8)
                  | ((unsigned)t.z << 16) | ((unsigned)t.w << 24);
        }
    }

    float s1 = 0.f, q1 = 0.f, s2 = 0.f, q2 = 0.f;
    unsigned cc = 1;                             // current organ id

    auto acc4 = [&](const float4 A, int k, float& q, float& s) {
        const unsigned t4 = tw[k];
        q = fmaf(A.x, A.x, q); q = fmaf(A.y, A.y, q);
        q = fmaf(A.z, A.z, q); q = fmaf(A.w, A.w, q);
        const bool ex = ((t4 & 255u) == cc);
        const bool ey = (((t4 >> 8) & 255u) == cc);
        const bool ez = (((t4 >> 16) & 255u) == cc);
        const bool ew = ((t4 >> 24) == cc);
        s += (ex ? A.x : 0.f) + (ey ? A.y : 0.f)
           + (ez ? A.z : 0.f) + (ew ? A.w : 0.f);
    };

    // One channel: consume 6 tiles (3 stage1 -> q1/s1, 3 stage2 -> q2/s2),
    // issue the next 6 (this channel's stage2, next channel's stage1).
    // Tile T = 6c+j, slot = T&3, SB = (6c)&3 alternates 0/2 per channel.
    auto chan = [&](int SB) {
        #pragma unroll
        for (int p = 0; p < 3; ++p) {
            asm volatile("s_waitcnt vmcnt(2)" ::: "memory");
            LOADLDS(a1 + p * TPB, (SB + p + 3) & 3);
            acc4(ring[(SB + p) & 3][tid], p, q1, s1);
        }
        #pragma unroll
        for (int p = 0; p < 3; ++p) {
            asm volatile("s_waitcnt vmcnt(2)" ::: "memory");
            LOADLDS(a0 + NV4 + p * TPB, (SB + p + 2) & 3);
            acc4(ring[(SB + p + 3) & 3][tid], p, q2, s2);
        }
        a0 += NV4; a1 += NV4; ++cc;
    };

    #pragma unroll 1
    for (int cp = 0; cp < 6; ++cp) { chan(0); chan(2); }   // channels 1..12

    // Peel last channel (cc==13, SB=0): issue its stage2, then drain.
    #pragma unroll
    for (int p = 0; p < 3; ++p) {
        asm volatile("s_waitcnt vmcnt(2)" ::: "memory");
        LOADLDS(a1 + p * TPB, (p + 3) & 3);
        acc4(ring[p][tid], p, q1, s1);
    }
    asm volatile("s_waitcnt vmcnt(2)" ::: "memory");
    acc4(ring[3][tid], 0, q2, s2);
    asm volatile("s_waitcnt vmcnt(1)" ::: "memory");
    acc4(ring[0][tid], 1, q2, s2);
    asm volatile("s_waitcnt vmcnt(0)" ::: "memory");
    acc4(ring[1][tid], 2, q2, s2);

    // ---- Block reduction: wave shuffle then LDS across 8 waves ----
    float vals[5] = {s1, q1, s2, q2, cn};
    #pragma unroll
    for (int k = 0; k < 5; ++k) {
        float v = vals[k];
        #pragma unroll
        for (int off = 32; off > 0; off >>= 1) v += __shfl_down(v, off, 64);
        vals[k] = v;
    }
    const int lane = tid & 63;
    if (lane == 0) {
        #pragma unroll
        for (int k = 0; k < 5; ++k) red[wid][k] = vals[k];
    }
    __syncthreads();
    if (tid == 0) {
        #pragma unroll
        for (int k = 0; k < 5; ++k) {
            float v = 0.f;
            #pragma unroll
            for (int w = 0; w < 8; ++w) v += red[w][k];
            part[blk * 5 + k] = (double)v;
        }
    }
}

__global__ __launch_bounds__(256) void dice_final(
    const double* __restrict__ part, float* __restrict__ out)
{
    __shared__ double redd[BATCH][4][5];
    const int tid = threadIdx.x, lane = tid & 63, wv = tid >> 6;
    #pragma unroll
    for (int b = 0; b < BATCH; ++b) {
        double loc[5] = {0, 0, 0, 0, 0};
        for (int i = tid; i < NBLK / BATCH; i += 256) {
            const double* p = part + ((unsigned)(b * (NBLK / BATCH) + i)) * 5u;
            #pragma unroll
            for (int k = 0; k < 5; ++k) loc[k] += p[k];
        }
        #pragma unroll
        for (int k = 0; k < 5; ++k) {
            double v = loc[k];
            #pragma unroll
            for (int off = 32; off > 0; off >>= 1) v += __shfl_down(v, off, 64);
            loc[k] = v;
        }
        if (lane == 0) {
            #pragma unroll
            for (int k = 0; k < 5; ++k) redd[b][wv][k] = loc[k];
        }
    }
    __syncthreads();
    if (tid == 0) {
        double total = 0.0;
        #pragma unroll
        for (int b = 0; b < BATCH; ++b) {
            double a[5];
            #pragma unroll
            for (int k = 0; k < 5; ++k)
                a[k] = redd[b][0][k] + redd[b][1][k] + redd[b][2][k] + redd[b][3][k];
            const double den1 = a[1] + a[4] + (double)ORGANS * EPS;
            const double den2 = a[3] + a[4] + (double)ORGANS * EPS;
            total += 2.0 - (2.0 * a[0] / den1 + 2.0 * a[2] / den2);
        }
        *out = (float)(total / BATCH);
    }
}

extern "C" void kernel_launch(void* const* d_in, const int* in_sizes, int n_in,
                              void* d_out, int out_size, void* d_ws, size_t ws_size,
                              hipStream_t stream)
{
    const float* p1 = (const float*)d_in[0];
    const float* p2 = (const float*)d_in[1];
    const int* tg = (const int*)d_in[2];
    float* out = (float*)d_out;
    double* part = (double*)d_ws;    // 1024*5 doubles = 40 KB; all written per call

    dice_lds<<<dim3(NBLK), dim3(TPB), 0, stream>>>(p1, p2, tg, part);
    dice_final<<<1, 256, 0, stream>>>(part, out);
}

// Round 12
// 138.795 us; speedup vs baseline: 1.1913x; 1.1464x over previous
//
#include <hip/hip_runtime.h>

// DiceLoss: B=2, C=14, D=48, H=256, W=256, organs 1..13, weights all 1.0.
// Per batch b: S = sum of pred at target channel (t in 1..13),
//              Q = sum over c=1..13 of pred[c]^2, cnt = #{t>=1}.
// dice_stage = 2S/(Q + cnt + 13*EPS); out = mean_b(2 - dice1 - dice2).
//
// FINAL (= R6, empirical optimum at 139 us): LDS ring via global_load_lds
// (width 16), counted vmcnt(2), zero barriers (each wave owns its ring
// quarter), 2 interleaved streams/block, 2048 blocks = 8/CU = 32 waves/CU.
// Axis map (wall us): streams {1:174, 2:139, 4:155}; waves/CU {16:144,
// 32:139}; TPB {256:139, 512:159}; NT policy -6%; dual return-path -19%;
// register-return path caps at 4.6 TB/s. All probes converge to a
// ~5.2-5.4 TB/s pure-read ceiling (~79% of the 6.8 TB/s write-fill rate).

namespace {
constexpr int BATCH = 2;
constexpr int CH = 14;
constexpr int ORGANS = 13;
constexpr unsigned NV4 = 786432u;        // vec4 groups per (b, channel) slice
constexpr int TPB = 256;
constexpr int NBLK = 2048;               // 1024 per batch, 8/CU exactly
constexpr unsigned WIN = 768u;           // groups per block window (1024*768 = NV4)
constexpr int KT = 3;                    // tiles per (c, stage): WIN/256
constexpr int TILES = ORGANS * 2 * KT;   // 78
constexpr int NBUF = 4;                  // ring slots (4 KB each) -> 16 KB
constexpr int DEPTH = 3;                 // tiles in flight per wave
constexpr double EPS = 1e-05;
}

__global__ __launch_bounds__(TPB, 8) void dice_lds(
    const float* __restrict__ p1g, const float* __restrict__ p2g,
    const int* __restrict__ tg, double* __restrict__ part)
{
    __shared__ float4 ring[NBUF][TPB];   // 16 KB ring
    __shared__ float red[4][5];

    const unsigned blk = blockIdx.x;
    const unsigned b = blk >> 10;                // batch
    const unsigned w0 = (blk & 1023u) * WIN;     // window start (groups)
    const unsigned tid = threadIdx.x;
    const unsigned wid = tid >> 6;

    // ---- Phase 0: target window once -> cnt + KT packed label words ----
    unsigned tw[KT];
    float cn = 0.f;
    {
        const int4* __restrict__ pT =
            reinterpret_cast<const int4*>(tg) + b * NV4 + w0;
        #pragma unroll
        for (int k = 0; k < KT; ++k) {
            const int4 t = pT[k * TPB + tid];
            cn += (float)((t.x > 0) + (t.y > 0) + (t.z > 0) + (t.w > 0));
            tw[k] = (unsigned)t.x | ((unsigned)t.y << 8)
                  | ((unsigned)t.z << 16) | ((unsigned)t.w << 24);
        }
    }

    // ---- Streaming phase: 78 tiles, ring of 4, depth 3, no barriers ----
    // Window base for channel 1 of each stage (float4 index space).
    const float4* __restrict__ pS0 =
        reinterpret_cast<const float4*>(p1g) + (unsigned long long)(b * CH + 1) * NV4 + w0;
    const float4* __restrict__ pS1 =
        reinterpret_cast<const float4*>(p2g) + (unsigned long long)(b * CH + 1) * NV4 + w0;
    const unsigned ldsq = wid * 64u;             // this wave's quarter (float4 idx)

    auto issue = [&](unsigned ti) {
        const unsigned ci = ti / (2u * KT);
        const unsigned rem = ti - ci * (2u * KT);
        const unsigned si = (rem >= (unsigned)KT) ? 1u : 0u;
        const unsigned ki = rem - si * (unsigned)KT;
        const float4* src = (si ? pS1 : pS0) + (ci * NV4 + ki * TPB + tid);
        const unsigned slot = ti & (NBUF - 1);
        __builtin_amdgcn_global_load_lds(
            (const __attribute__((address_space(1))) unsigned*)src,
            (__attribute__((address_space(3))) unsigned*)&ring[slot][ldsq],
            16, 0, 0);
    };

    for (unsigned ti = 0; ti < (unsigned)DEPTH; ++ti) issue(ti);

    float s1 = 0.f, q1 = 0.f, s2 = 0.f, q2 = 0.f;
    unsigned ti = 0;
    for (unsigned c = 0; c < (unsigned)ORGANS; ++c) {
        const unsigned cc = c + 1u;
        #pragma unroll
        for (int s = 0; s < 2; ++s) {
            #pragma unroll
            for (int k = 0; k < KT; ++k, ++ti) {
                if (ti + DEPTH < (unsigned)TILES) {
                    // keep DEPTH in flight; wait only until tile ti landed
                    asm volatile("s_waitcnt vmcnt(2)" ::: "memory");
                    issue(ti + DEPTH);
                } else {
                    asm volatile("s_waitcnt vmcnt(0)" ::: "memory");
                }
                const float4 A = ring[ti & (NBUF - 1)][tid];
                const unsigned t4 = tw[k];
                const bool ex = ((t4 & 255u) == cc);
                const bool ey = (((t4 >> 8) & 255u) == cc);
                const bool ez = (((t4 >> 16) & 255u) == cc);
                const bool ew = ((t4 >> 24) == cc);
                if (s == 0) {
                    q1 = fmaf(A.x, A.x, q1); q1 = fmaf(A.y, A.y, q1);
                    q1 = fmaf(A.z, A.z, q1); q1 = fmaf(A.w, A.w, q1);
                    s1 += (ex ? A.x : 0.f) + (ey ? A.y : 0.f)
                        + (ez ? A.z : 0.f) + (ew ? A.w : 0.f);
                } else {
                    q2 = fmaf(A.x, A.x, q2); q2 = fmaf(A.y, A.y, q2);
                    q2 = fmaf(A.z, A.z, q2); q2 = fmaf(A.w, A.w, q2);
                    s2 += (ex ? A.x : 0.f) + (ey ? A.y : 0.f)
                        + (ez ? A.z : 0.f) + (ew ? A.w : 0.f);
                }
            }
        }
    }

    // ---- Block reduction: wave shuffle then LDS across 4 waves ----
    float vals[5] = {s1, q1, s2, q2, cn};
    #pragma unroll
    for (int k = 0; k < 5; ++k) {
        float v = vals[k];
        #pragma unroll
        for (int off = 32; off > 0; off >>= 1) v += __shfl_down(v, off, 64);
        vals[k] = v;
    }
    const int lane = tid & 63;
    if (lane == 0) {
        #pragma unroll
        for (int k = 0; k < 5; ++k) red[wid][k] = vals[k];
    }
    __syncthreads();
    if (tid == 0) {
        #pragma unroll
        for (int k = 0; k < 5; ++k)
            part[blk * 5 + k] =
                (double)(red[0][k] + red[1][k] + red[2][k] + red[3][k]);
    }
}

__global__ __launch_bounds__(256) void dice_final(
    const double* __restrict__ part, float* __restrict__ out)
{
    __shared__ double redd[BATCH][4][5];
    const int tid = threadIdx.x, lane = tid & 63, wv = tid >> 6;
    #pragma unroll
    for (int b = 0; b < BATCH; ++b) {
        double loc[5] = {0, 0, 0, 0, 0};
        for (int i = tid; i < NBLK / BATCH; i += 256) {
            const double* p = part + ((unsigned)(b * (NBLK / BATCH) + i)) * 5u;
            #pragma unroll
            for (int k = 0; k < 5; ++k) loc[k] += p[k];
        }
        #pragma unroll
        for (int k = 0; k < 5; ++k) {
            double v = loc[k];
            #pragma unroll
            for (int off = 32; off > 0; off >>= 1) v += __shfl_down(v, off, 64);
            loc[k] = v;
        }
        if (lane == 0) {
            #pragma unroll
            for (int k = 0; k < 5; ++k) redd[b][wv][k] = loc[k];
        }
    }
    __syncthreads();
    if (tid == 0) {
        double total = 0.0;
        #pragma unroll
        for (int b = 0; b < BATCH; ++b) {
            double a[5];
            #pragma unroll
            for (int k = 0; k < 5; ++k)
                a[k] = redd[b][0][k] + redd[b][1][k] + redd[b][2][k] + redd[b][3][k];
            const double den1 = a[1] + a[4] + (double)ORGANS * EPS;
            const double den2 = a[3] + a[4] + (double)ORGANS * EPS;
            total += 2.0 - (2.0 * a[0] / den1 + 2.0 * a[2] / den2);
        }
        *out = (float)(total / BATCH);
    }
}

extern "C" void kernel_launch(void* const* d_in, const int* in_sizes, int n_in,
                              void* d_out, int out_size, void* d_ws, size_t ws_size,
                              hipStream_t stream)
{
    const float* p1 = (const float*)d_in[0];
    const float* p2 = (const float*)d_in[1];
    const int* tg = (const int*)d_in[2];
    float* out = (float*)d_out;
    double* part = (double*)d_ws;    // 2048*5 doubles = 80 KB; all written per call

    dice_lds<<<dim3(NBLK), dim3(TPB), 0, stream>>>(p1, p2, tg, part);
    dice_final<<<1, 256, 0, stream>>>(part, out);
}